// Round 8
// baseline (225.479 us; speedup 1.0000x reference)
//
#include <hip/hip_runtime.h>
#include <hip/hip_bf16.h>

#define BB 32
#define LL 512
#define DD 1024
#define NHD 1024
#define EE 128
#define NCOL 120
#define KTOK 4
#define TOPKN 6
#define MROWS (BB * NCOL)   // 3840

typedef __attribute__((ext_vector_type(8))) _Float16 f16x8;
typedef __attribute__((ext_vector_type(4))) float f32x4;

__device__ inline ushort f2h(float x) {
    _Float16 h = (_Float16)x;              // RNE via v_cvt_f16_f32
    union { _Float16 h; ushort u; } c;
    c.h = h;
    return c.u;
}

// ---------------------------------------------------------------------------
// K1: ee_h[b,e,:] = fp16( sum_k q_enc[b, tok[e,k], :] )
// grid = B*E = 4096 blocks, 256 threads, float4 per thread.
// Side duty (folded init, saves a launch):
//   blocks 0..14   : att[be*256+t] = b_o2[0]        (3840 elements)
//   blocks 15..142 : H[(be-15)*256+t] = b_t1[j&1023] (32768 elements)
// ---------------------------------------------------------------------------
__global__ __launch_bounds__(256) void ee_kernel(const float* __restrict__ q,
                                                 const int* __restrict__ tok,
                                                 ushort* __restrict__ ee,
                                                 float* __restrict__ att,
                                                 const float* __restrict__ b_o2,
                                                 float* __restrict__ H,
                                                 const float* __restrict__ b_t1) {
    int be = blockIdx.x;
    int b  = be >> 7;
    int e  = be & 127;
    int t  = threadIdx.x;

    if (be < 15) {
        att[be * 256 + t] = b_o2[0];
    } else if (be < 15 + 128) {
        int j = (be - 15) * 256 + t;
        H[j] = b_t1[j & (NHD - 1)];
    }

    const float* qb = q + (size_t)b * LL * DD;
    int t0 = tok[e * KTOK + 0];
    int t1 = tok[e * KTOK + 1];
    int t2 = tok[e * KTOK + 2];
    int t3 = tok[e * KTOK + 3];
    int f = t * 4;
    float4 a = *(const float4*)(qb + (size_t)t0 * DD + f);
    float4 bv = *(const float4*)(qb + (size_t)t1 * DD + f);
    float4 c = *(const float4*)(qb + (size_t)t2 * DD + f);
    float4 d = *(const float4*)(qb + (size_t)t3 * DD + f);
    ushort4 o;
    o.x = f2h(a.x + bv.x + c.x + d.x);
    o.y = f2h(a.y + bv.y + c.y + d.y);
    o.z = f2h(a.z + bv.z + c.z + d.z);
    o.w = f2h(a.w + bv.w + c.w + d.w);
    *(ushort4*)(ee + (size_t)be * DD + f) = o;
}

// ---------------------------------------------------------------------------
// Pack W [D][N] fp32 -> fp16 MFMA B-fragment order (3 weights in one launch):
//   pk[ ((nb*32 + kb)*64 + lane)*8 + j ] = W[kb*32 + 8*(lane>>4) + j][nb*16 + (lane&15)]
// ---------------------------------------------------------------------------
__global__ __launch_bounds__(256) void pack_w_kernel(
    const float* __restrict__ W0, const float* __restrict__ W1f,
    const float* __restrict__ W2f, ushort* __restrict__ pk0,
    ushort* __restrict__ pk1, ushort* __restrict__ pk2) {
    const float* W = blockIdx.y == 0 ? W0 : (blockIdx.y == 1 ? W1f : W2f);
    ushort* pk     = blockIdx.y == 0 ? pk0 : (blockIdx.y == 1 ? pk1 : pk2);
    int idx = blockIdx.x * 256 + threadIdx.x;    // 0 .. 131071
    int l  = idx & 63;
    int kb = (idx >> 6) & 31;
    int nb = idx >> 11;
    int row = kb * 32 + (l >> 4) * 8;
    int col = nb * 16 + (l & 15);
    ushort o[8];
#pragma unroll
    for (int j = 0; j < 8; ++j)
        o[j] = f2h(W[(size_t)(row + j) * NHD + col]);
    ulong2 v;
    v.x = ((ulong)o[0]) | ((ulong)o[1] << 16) | ((ulong)o[2] << 32) | ((ulong)o[3] << 48);
    v.y = ((ulong)o[4]) | ((ulong)o[5] << 16) | ((ulong)o[6] << 32) | ((ulong)o[7] << 48);
    *(ulong2*)(pk + (size_t)idx * 8) = v;
}

// ---------------------------------------------------------------------------
// GEMM1: fused[r,f] = fp16( ee[b,ci[i],:].Wc[:,f] + ee[b,ti[i],:].Wt[:,f]
//                            + bc[f] + bt[f] ),  r = b*120+i
// Block tile 128x64, 4 waves (2x2), wave tile 64x32 (4 M-frag x 2 N-frag).
// No LDS / no barriers; register double-buffered K-loop (2 steps in flight).
// ---------------------------------------------------------------------------
__global__ __launch_bounds__(256) void gemm1_kernel(
    const ushort* __restrict__ ee, const int* __restrict__ ci, const int* __restrict__ ti,
    const ushort* __restrict__ Wc_pk, const ushort* __restrict__ Wt_pk,
    const float* __restrict__ bc, const float* __restrict__ bt,
    ushort* __restrict__ fused) {
    int t = threadIdx.x;
    int l = t & 63;
    int w = t >> 6;
    int wm = w >> 1, wn = w & 1;
    int row0 = blockIdx.x * 128 + wm * 64;
    int col0 = blockIdx.y * 64 + wn * 32;
    int nb0  = col0 >> 4;
    int koff = (l >> 4) * 8;

    const ushort* arow0[4];
    const ushort* arow1[4];
#pragma unroll
    for (int m = 0; m < 4; ++m) {
        int r = row0 + m * 16 + (l & 15);
        int b = r / NCOL;
        int i = r - b * NCOL;
        arow0[m] = ee + ((size_t)(b * EE + ci[i])) * DD;
        arow1[m] = ee + ((size_t)(b * EE + ti[i])) * DD;
    }

    f32x4 acc[4][2] = {};

#pragma unroll
    for (int phase = 0; phase < 2; ++phase) {
        const ushort* Wp = phase ? Wt_pk : Wc_pk;
        const ushort* const* ar = phase ? arow1 : arow0;

        f16x8 aA[4], bA[2], aB[4], bB[2];

#define LOAD_FR(AV, BV, kb)                                                     \
        {                                                                       \
            _Pragma("unroll")                                                   \
            for (int m = 0; m < 4; ++m)                                         \
                AV[m] = *(const f16x8*)(ar[m] + (kb) * 32 + koff);              \
            _Pragma("unroll")                                                   \
            for (int n = 0; n < 2; ++n)                                         \
                BV[n] = *(const f16x8*)(Wp + (((size_t)(nb0 + n) * 32 + (kb)) * 64 + l) * 8); \
        }
#define MFMA_FR(AV, BV)                                                         \
        {                                                                       \
            _Pragma("unroll")                                                   \
            for (int m = 0; m < 4; ++m)                                         \
                _Pragma("unroll")                                               \
                for (int n = 0; n < 2; ++n)                                     \
                    acc[m][n] = __builtin_amdgcn_mfma_f32_16x16x32_f16(         \
                        AV[m], BV[n], acc[m][n], 0, 0, 0);                      \
        }

        LOAD_FR(aA, bA, 0)
#pragma unroll 1
        for (int kb = 0; kb < 30; kb += 2) {
            LOAD_FR(aB, bB, kb + 1)
            MFMA_FR(aA, bA)
            LOAD_FR(aA, bA, kb + 2)
            MFMA_FR(aB, bB)
        }
        LOAD_FR(aB, bB, 31)
        MFMA_FR(aA, bA)
        MFMA_FR(aB, bB)
#undef LOAD_FR
#undef MFMA_FR
    }

    float badd[2];
#pragma unroll
    for (int n = 0; n < 2; ++n) {
        int c = col0 + n * 16 + (l & 15);
        badd[n] = bc[c] + bt[c];
    }
    int rlane = (l >> 4) * 4;
#pragma unroll
    for (int m = 0; m < 4; ++m)
#pragma unroll
        for (int n = 0; n < 2; ++n) {
            int c = col0 + n * 16 + (l & 15);
#pragma unroll
            for (int j = 0; j < 4; ++j) {
                int r = row0 + m * 16 + rlane + j;
                fused[(size_t)r * NHD + c] = f2h(acc[m][n][j] + badd[n]);
            }
        }
}

// ---------------------------------------------------------------------------
// GEMM2: h = relu(fused @ W_o1 + b_o1); att[r] += h . W_o2   (h in regs only)
// Same structure as GEMM1; epilogue: relu + W_o2 dot + shfl reduce + atomicAdd.
// ---------------------------------------------------------------------------
__global__ __launch_bounds__(256) void gemm2_kernel(
    const ushort* __restrict__ fused, const ushort* __restrict__ W1_pk,
    const float* __restrict__ b1, const float* __restrict__ W2,
    float* __restrict__ att) {
    int t = threadIdx.x;
    int l = t & 63;
    int w = t >> 6;
    int wm = w >> 1, wn = w & 1;
    int row0 = blockIdx.x * 128 + wm * 64;
    int col0 = blockIdx.y * 64 + wn * 32;
    int nb0  = col0 >> 4;
    int koff = (l >> 4) * 8;

    const ushort* arow[4];
#pragma unroll
    for (int m = 0; m < 4; ++m)
        arow[m] = fused + (size_t)(row0 + m * 16 + (l & 15)) * NHD;

    f32x4 acc[4][2] = {};
    f16x8 aA[4], bA[2], aB[4], bB[2];

#define LOAD_FR(AV, BV, kb)                                                     \
    {                                                                           \
        _Pragma("unroll")                                                       \
        for (int m = 0; m < 4; ++m)                                             \
            AV[m] = *(const f16x8*)(arow[m] + (kb) * 32 + koff);                \
        _Pragma("unroll")                                                       \
        for (int n = 0; n < 2; ++n)                                             \
            BV[n] = *(const f16x8*)(W1_pk + (((size_t)(nb0 + n) * 32 + (kb)) * 64 + l) * 8); \
    }
#define MFMA_FR(AV, BV)                                                         \
    {                                                                           \
        _Pragma("unroll")                                                       \
        for (int m = 0; m < 4; ++m)                                             \
            _Pragma("unroll")                                                   \
            for (int n = 0; n < 2; ++n)                                         \
                acc[m][n] = __builtin_amdgcn_mfma_f32_16x16x32_f16(             \
                    AV[m], BV[n], acc[m][n], 0, 0, 0);                          \
    }

    LOAD_FR(aA, bA, 0)
#pragma unroll 1
    for (int kb = 0; kb < 30; kb += 2) {
        LOAD_FR(aB, bB, kb + 1)
        MFMA_FR(aA, bA)
        LOAD_FR(aA, bA, kb + 2)
        MFMA_FR(aB, bB)
    }
    LOAD_FR(aB, bB, 31)
    MFMA_FR(aA, bA)
    MFMA_FR(aB, bB)
#undef LOAD_FR
#undef MFMA_FR

    float bo[2], wo[2];
#pragma unroll
    for (int n = 0; n < 2; ++n) {
        int c = col0 + n * 16 + (l & 15);
        bo[n] = b1[c];
        wo[n] = W2[c];
    }
    int rlane = (l >> 4) * 4;
#pragma unroll
    for (int m = 0; m < 4; ++m) {
#pragma unroll
        for (int j = 0; j < 4; ++j) {
            float p = 0.f;
#pragma unroll
            for (int n = 0; n < 2; ++n) {
                float h = fmaxf(acc[m][n][j] + bo[n], 0.f);
                p = fmaf(h, wo[n], p);
            }
            p += __shfl_xor(p, 1);
            p += __shfl_xor(p, 2);
            p += __shfl_xor(p, 4);
            p += __shfl_xor(p, 8);
            if ((l & 15) == 0)
                atomicAdd(&att[row0 + m * 16 + rlane + j], p);
        }
    }
}

// ---------------------------------------------------------------------------
// K5a: H[b,f] += cls[b, k-chunk] @ W_t1[k-chunk, f-chunk]   (fp32, atomics)
// grid = (64 f-chunks of 16, 8 k-chunks of 128); W_t1 read exactly once.
// ---------------------------------------------------------------------------
__global__ __launch_bounds__(256) void topk_h_kernel(const float* __restrict__ q,
                                                     const float* __restrict__ W1,
                                                     float* __restrict__ H) {
    __shared__ float cls[BB][128];
    __shared__ float wsh[128][17];
    int f0 = blockIdx.x * 16;
    int k0 = blockIdx.y * 128;
    int t = threadIdx.x;
#pragma unroll
    for (int m = 0; m < 16; ++m) {
        int idx = t + m * 256;              // 0..4095
        int b = idx >> 7, d = idx & 127;
        cls[b][d] = q[(size_t)b * LL * DD + k0 + d];
    }
#pragma unroll
    for (int m = 0; m < 8; ++m) {
        int idx = t + m * 256;              // 0..2047
        int r = idx >> 4, c = idx & 15;
        wsh[r][c] = W1[(size_t)(k0 + r) * NHD + f0 + c];
    }
    __syncthreads();
    int f = t & 15;
    int b0 = t >> 4;                        // 0..15
#pragma unroll
    for (int h = 0; h < 2; ++h) {
        int b = b0 + h * 16;
        float s = 0.f;
#pragma unroll 8
        for (int d = 0; d < 128; ++d)
            s = fmaf(cls[b][d], wsh[d][f], s);
        atomicAdd(&H[(size_t)b * NHD + f0 + f], s);
    }
}

// ---------------------------------------------------------------------------
// K5b: topk[b,:] = sigmoid(relu(H[b,:]) @ W_t2 + b_t2)
// ---------------------------------------------------------------------------
__global__ __launch_bounds__(256) void topk_out_kernel(
    const float* __restrict__ H, const float* __restrict__ W2,
    const float* __restrict__ b2, float* __restrict__ outp) {
    __shared__ float red[4][TOPKN];
    int b = blockIdx.x;
    int t = threadIdx.x;
    float part[TOPKN] = {};
#pragma unroll
    for (int m = 0; m < 4; ++m) {
        int f = t + m * 256;
        float h = fmaxf(H[(size_t)b * NHD + f], 0.f);
#pragma unroll
        for (int k = 0; k < TOPKN; ++k)
            part[k] = fmaf(h, W2[f * TOPKN + k], part[k]);
    }
#pragma unroll
    for (int k = 0; k < TOPKN; ++k) {
        float v = part[k];
        for (int off = 1; off < 64; off <<= 1) v += __shfl_xor(v, off);
        part[k] = v;
    }
    int wave = t >> 6, lane = t & 63;
    if (lane == 0)
#pragma unroll
        for (int k = 0; k < TOPKN; ++k) red[wave][k] = part[k];
    __syncthreads();
    if (t == 0)
#pragma unroll
        for (int k = 0; k < TOPKN; ++k) {
            float s = red[0][k] + red[1][k] + red[2][k] + red[3][k] + b2[k];
            outp[b * TOPKN + k] = 1.f / (1.f + __expf(-s));
        }
}

// ---------------------------------------------------------------------------
extern "C" void kernel_launch(void* const* d_in, const int* in_sizes, int n_in,
                              void* d_out, int out_size, void* d_ws, size_t ws_size,
                              hipStream_t stream) {
    const float* q_enc   = (const float*)d_in[0];
    const int*   etok    = (const int*)  d_in[1];
    const int*   ci      = (const int*)  d_in[2];
    const int*   ti      = (const int*)  d_in[3];
    const float* W_table = (const float*)d_in[4];
    const float* b_table = (const float*)d_in[5];
    const float* W_col   = (const float*)d_in[6];
    const float* b_col   = (const float*)d_in[7];
    const float* W_o1    = (const float*)d_in[8];
    const float* b_o1    = (const float*)d_in[9];
    const float* W_o2    = (const float*)d_in[10];
    const float* b_o2    = (const float*)d_in[11];
    const float* W_t1    = (const float*)d_in[12];
    const float* b_t1    = (const float*)d_in[13];
    const float* W_t2    = (const float*)d_in[14];
    const float* b_t2    = (const float*)d_in[15];

    float* outp = (float*)d_out;
    float* att  = outp;            // 3840
    float* topk = outp + MROWS;    // 192

    // workspace layout (bytes)
    char* ws = (char*)d_ws;
    ushort* ee_h    = (ushort*)(ws);                          // 4,194,304 fp16
    ushort* fused   = (ushort*)(ws + 8388608);                // 3,932,160 fp16
    ushort* Wc_pk   = (ushort*)(ws + 16252928);               // 1,048,576 fp16
    ushort* Wt_pk   = (ushort*)(ws + 18350080);               // 1,048,576 fp16
    ushort* Wo1_pk  = (ushort*)(ws + 20447232);               // 1,048,576 fp16
    float*  H       = (float*) (ws + 22544384);               // 32,768 f32

    hipLaunchKernelGGL(ee_kernel, dim3(BB * EE), dim3(256), 0, stream,
                       q_enc, etok, ee_h, att, b_o2, H, b_t1);
    hipLaunchKernelGGL(pack_w_kernel, dim3(512, 3), dim3(256), 0, stream,
                       W_col, W_table, W_o1, Wc_pk, Wt_pk, Wo1_pk);
    hipLaunchKernelGGL(gemm1_kernel, dim3(MROWS / 128, NHD / 64), dim3(256), 0, stream,
                       ee_h, ci, ti, Wc_pk, Wt_pk, b_col, b_table, fused);
    hipLaunchKernelGGL(gemm2_kernel, dim3(MROWS / 128, NHD / 64), dim3(256), 0, stream,
                       fused, Wo1_pk, b_o1, W_o2, att);
    hipLaunchKernelGGL(topk_h_kernel, dim3(64, 8), dim3(256), 0, stream, q_enc, W_t1, H);
    hipLaunchKernelGGL(topk_out_kernel, dim3(BB), dim3(256), 0, stream, H, W_t2, b_t2, topk);
}